// Round 9
// baseline (315.619 us; speedup 1.0000x reference)
//
#include <hip/hip_runtime.h>

#define TOPK 13
#define NCLS 80
#define EPSF 1e-9f
#define NSEG 24
#define GPB  8            // GTs per block (one per wave at selection time)
#define CAP3 512          // per-g candidate p-indices (mean ~270 incl forced, sd ~16)
#define MCAP (64 * TOPK)  // merge scratch entries per wave (832 float2 = 6656 B)

// ---------------------------------------------------------------------------
// setup: block 0 sorts GTs by (class,g) -> gorder; blocks 1.. init
// count[P]=0 / firstg[P]=INT_MAX with int4 stores.
// ---------------------------------------------------------------------------
__global__ __launch_bounds__(256) void setup(const int* __restrict__ lbl,
                                             int* __restrict__ count,
                                             int* __restrict__ firstg,
                                             int* __restrict__ gorder, int P, int N) {
    int t = threadIdx.x;
    if (blockIdx.x == 0) {
        __shared__ int key[256];
        key[t] = (t < N) ? ((lbl[t] << 8) | t) : 0x7FFFFFFF;
        __syncthreads();
        for (int k = 2; k <= 256; k <<= 1) {
            for (int j = k >> 1; j >= 1; j >>= 1) {
                int ixj = t ^ j;
                if (ixj > t) {
                    int a = key[t], b = key[ixj];
                    bool up = ((t & k) == 0);
                    if (up ? (a > b) : (a < b)) { key[t] = b; key[ixj] = a; }
                }
                __syncthreads();
            }
        }
        if (t < N) gorder[t] = key[t] & 0xFF;
    } else {
        int base = (blockIdx.x - 1) * 1024 + t * 4;
        if (base + 3 < P) {
            *(int4*)&count[base]  = make_int4(0, 0, 0, 0);
            *(int4*)&firstg[base] = make_int4(0x7FFFFFFF, 0x7FFFFFFF, 0x7FFFFFFF, 0x7FFFFFFF);
        } else {
            for (int i = base; i < P; i++) { count[i] = 0; firstg[i] = 0x7FFFFFFF; }
        }
    }
}

// ---------------------------------------------------------------------------
// phaseA1: grid (NSEG=24, N/8) = 768 blocks = exactly 3/CU. 512 threads.
// LDS 53.3KB: pbuf aliases the first 16KB of mbuf (disjoint live ranges,
// block barrier between eval-reads and merge-writes — proven in R7).
// HOT: peeled + 4x-unrolled overlap filter -> per-g LDS p-lists.
// SPARSE: wave wv exactly evaluates g-slot wv's candidates, per-lane top-13
// with (m desc, p asc) total order, LDS tree merge, write 13 to cand.
// NO device fences (R7 lesson); global reduction stays in phaseA2.
// ---------------------------------------------------------------------------
__global__ __launch_bounds__(512, 6) void phaseA1(const float* __restrict__ cls,
                                                  const float4* __restrict__ bboxp,
                                                  const float4* __restrict__ bboxg,
                                                  const int* __restrict__ lbl,
                                                  const int* __restrict__ gorder,
                                                  float2* __restrict__ cand,
                                                  int P, int N, int seglen) {
#pragma clang fp contract(off)
    const int s = blockIdx.x, tile = blockIdx.y, t = threadIdx.x;
    const int wv = t >> 6, lane = t & 63;
    const int pstart = s * seglen;
    int pend = pstart + seglen; if (pend > P) pend = P;

    __shared__ float2 mbuf[GPB][MCAP];   // 53248 B; first 16 KB doubles as pbuf
    __shared__ int ctr[GPB];
    int* pbuf = (int*)&mbuf[0][0];       // pbuf[j*CAP3 + slot], j<8 -> 16 KB

    float4 gb[GPB];
#pragma unroll
    for (int j = 0; j < GPB; j++) {
        int gi8 = tile * GPB + j;
        int gj = (gi8 < N) ? gorder[gi8] : -1;
        gb[j] = (gj >= 0) ? bboxg[gj] : make_float4(0.f, 0.f, 0.f, 0.f);
    }
    if (t < GPB) ctr[t] = 0;
    __syncthreads();

    auto testapp = [&](float4 pb, int p, bool force) {
#pragma unroll
        for (int j = 0; j < GPB; j++) {
            float dx = fminf(gb[j].z, pb.z) - fmaxf(gb[j].x, pb.x);
            float dy = fminf(gb[j].w, pb.w) - fmaxf(gb[j].y, pb.y);
            bool want = ((dx > 0.0f) && (dy > 0.0f)) || force;
            if (want) {
                int slot = atomicAdd(&ctr[j], 1);
                if (slot < CAP3) pbuf[j * CAP3 + slot] = p;
            }
        }
    };

    // peeled first element carries the forced-16 candidates (zero-pool ties)
    int p = pstart + t;
    if (p < pend) { testapp(bboxp[p], p, t < 16); p += 512; }
    for (; p + 1536 < pend; p += 2048) {   // 4 independent loads in flight
        float4 pb0 = bboxp[p];
        float4 pb1 = bboxp[p + 512];
        float4 pb2 = bboxp[p + 1024];
        float4 pb3 = bboxp[p + 1536];
        testapp(pb0, p, false);
        testapp(pb1, p + 512, false);
        testapp(pb2, p + 1024, false);
        testapp(pb3, p + 1536, false);
    }
    for (; p < pend; p += 512) testapp(bboxp[p], p, false);
    __syncthreads();

    // ---- SPARSE exact evaluation: wave wv owns g-slot wv ----
    const int gi8 = tile * GPB + wv;
    const bool myValid = gi8 < N;
    const int gj = myValid ? gorder[gi8] : 0;
    const float4 gbw = bboxg[gj];
    const float gaw = fmaxf(gbw.z - gbw.x, 0.0f) * fmaxf(gbw.w - gbw.y, 0.0f);
    const int cidx = lbl[gj] - 1;
    const int rawtotal = ctr[wv];

    float v[TOPK]; int id[TOPK];
#pragma unroll
    for (int k = 0; k < TOPK; k++) { v[k] = -1.0f; id[k] = 0x7FFFFFFF; }

    auto ins = [&](float m, int pp) {
        bool b12 = (m > v[TOPK - 1]) || (m == v[TOPK - 1] && pp < id[TOPK - 1]);
        if (b12) {
#pragma unroll
            for (int k = TOPK - 1; k >= 1; k--) {
                bool a = (m > v[k - 1]) || (m == v[k - 1] && pp < id[k - 1]);
                bool b = (m > v[k]) || (m == v[k] && pp < id[k]);
                float nv = a ? v[k - 1] : (b ? m : v[k]);
                int   ni = a ? id[k - 1] : (b ? pp : id[k]);
                v[k] = nv; id[k] = ni;
            }
            bool a0 = (m > v[0]) || (m == v[0] && pp < id[0]);
            if (a0) { v[0] = m; id[0] = pp; }
        }
    };

    if (rawtotal <= CAP3) {
        for (int e = lane; e < rawtotal; e += 64) {
            int pp = pbuf[wv * CAP3 + e];
            float4 pb = bboxp[pp];
            float sc = cls[(size_t)pp * NCLS + cidx];
            float pa = fmaxf(pb.z - pb.x, 0.0f) * fmaxf(pb.w - pb.y, 0.0f);
            float xx1 = fmaxf(gbw.x, pb.x), yy1 = fmaxf(gbw.y, pb.y);
            float xx2 = fminf(gbw.z, pb.z), yy2 = fminf(gbw.w, pb.w);
            float inter = fmaxf(xx2 - xx1, 0.0f) * fmaxf(yy2 - yy1, 0.0f);
            float iou = inter / (((gaw + pa) - inter) + EPSF);
            float i2 = iou * iou;
            float m = sc * ((i2 * i2) * i2);
            ins(m, pp);
        }
    } else if (myValid) {
        for (int pp = pstart + lane; pp < pend; pp += 64) {  // exact cold fallback
            float4 pb = bboxp[pp];
            float sc = cls[(size_t)pp * NCLS + cidx];
            float pa = fmaxf(pb.z - pb.x, 0.0f) * fmaxf(pb.w - pb.y, 0.0f);
            float xx1 = fmaxf(gbw.x, pb.x), yy1 = fmaxf(gbw.y, pb.y);
            float xx2 = fminf(gbw.z, pb.z), yy2 = fminf(gbw.w, pb.w);
            float inter = fmaxf(xx2 - xx1, 0.0f) * fmaxf(yy2 - yy1, 0.0f);
            float iou = inter / (((gaw + pa) - inter) + EPSF);
            float i2 = iou * iou;
            float m = sc * ((i2 * i2) * i2);
            ins(m, pp);
        }
    }
    __syncthreads();   // ALL waves' pbuf reads done before merge overwrites alias

    // ---- per-wave LDS tree merge (each wave owns mbuf[wv]) ----
    float2* wl = mbuf[wv];
#pragma unroll
    for (int k = 0; k < TOPK; k++)
        wl[lane * TOPK + k] = make_float2(v[k], __int_as_float(id[k]));
    __syncthreads();
    for (int str = 32; str >= 1; str >>= 1) {
        if (lane < str) {
            float2 merged[TOPK];
            int a = 0, b = 0;
            const int ba = lane * TOPK, bb = (lane + str) * TOPK;
#pragma unroll
            for (int k = 0; k < TOPK; k++) {
                float2 fa = wl[ba + a], fb = wl[bb + b];
                int ia = __float_as_int(fa.y), ib = __float_as_int(fb.y);
                bool takeA = (fa.x > fb.x) || (fa.x == fb.x && ia < ib);
                merged[k] = takeA ? fa : fb;
                a += takeA; b += !takeA;
            }
#pragma unroll
            for (int k = 0; k < TOPK; k++) wl[ba + k] = merged[k];
        }
        __syncthreads();
    }
    if (lane < TOPK && myValid)
        cand[((size_t)gj * NSEG + s) * TOPK + lane] = wl[lane];
}

// ---------------------------------------------------------------------------
// phaseA2: per GT merge NSEG*13=312 candidates -> exact global top-13 via a
// 512-element bitonic sort, then scatter count/firstg atomics if max > eps.
// ---------------------------------------------------------------------------
__global__ __launch_bounds__(512) void phaseA2(const float2* __restrict__ cand,
                                               int* __restrict__ count,
                                               int* __restrict__ firstg) {
    const int g = blockIdx.x;
    const int t = threadIdx.x;
    const int M = NSEG * TOPK;  // 312
    __shared__ float cv[512];
    __shared__ int   ci[512];
    if (t < M) {
        float2 e = cand[(size_t)g * M + t];
        cv[t] = e.x; ci[t] = __float_as_int(e.y);
    } else {
        cv[t] = -1.0f; ci[t] = 0x7FFFFFFF;
    }
    __syncthreads();
    for (int k = 2; k <= 512; k <<= 1) {
        for (int j = k >> 1; j >= 1; j >>= 1) {
            int ixj = t ^ j;
            if (ixj > t) {
                float va = cv[t], vb = cv[ixj];
                int   ia = ci[t], ib = ci[ixj];
                bool aBeforeB = (va > vb) || (va == vb && ia < ib);
                bool dirFwd = ((t & k) == 0);
                bool doswap = dirFwd ? !aBeforeB : aBeforeB;
                if (doswap) { cv[t] = vb; ci[t] = ib; cv[ixj] = va; ci[ixj] = ia; }
            }
            __syncthreads();
        }
    }
    if (t < TOPK && cv[0] > EPSF) {
        int pi = ci[t];
        atomicAdd(&count[pi], 1);
        atomicMin(&firstg[pi], g);
    }
}

// ---------------------------------------------------------------------------
// phaseCF (ws path): fused resolve + all outputs, dense coalesced writes.
// ---------------------------------------------------------------------------
__global__ __launch_bounds__(256) void phaseCF(const float4* __restrict__ bboxp,
                                               const float4* __restrict__ bboxg,
                                               const int* __restrict__ lbl,
                                               const int* __restrict__ count,
                                               const int* __restrict__ firstg,
                                               float* __restrict__ out0,
                                               float* __restrict__ out1,
                                               float4* __restrict__ outcls4,
                                               float4* __restrict__ outbox4, int P, int N) {
#pragma clang fp contract(off)
    __shared__ float4 gbS[256];
    __shared__ int glS[256];
    __shared__ int clsl[256];
    int t = threadIdx.x;
    if (t < N) { gbS[t] = bboxg[t]; glS[t] = lbl[t]; }
    __syncthreads();
    int p0 = blockIdx.x * 256;
    int nloc = P - p0; if (nloc > 256) nloc = 256;
    if (t < nloc) {
        int p = p0 + t;
        int cnt = count[p];
        int gi = 0, pos = 0;
        if (cnt == 1) { gi = firstg[p]; pos = 1; }
        else if (cnt > 1) {
            float4 pb = bboxp[p];
            float pa = fmaxf(pb.z - pb.x, 0.0f) * fmaxf(pb.w - pb.y, 0.0f);
            float best = -1.0f;
            for (int g = 0; g < N; g++) {
                float4 g4 = gbS[g];
                float gar = fmaxf(g4.z - g4.x, 0.0f) * fmaxf(g4.w - g4.y, 0.0f);
                float xx1 = fmaxf(g4.x, pb.x), yy1 = fmaxf(g4.y, pb.y);
                float xx2 = fminf(g4.z, pb.z), yy2 = fminf(g4.w, pb.w);
                float inter = fmaxf(xx2 - xx1, 0.0f) * fmaxf(yy2 - yy1, 0.0f);
                float iou = inter / (((gar + pa) - inter) + EPSF);
                if (iou > best) { best = iou; gi = g; }   // strict > == first-max
            }
            pos = 1;
        }
        out0[p] = (float)gi;
        out1[p] = pos ? (float)glS[gi] : 0.0f;
        clsl[t] = glS[gi] - 1;
        outbox4[p] = gbS[gi];
    }
    __syncthreads();
    for (int f = t; f < nloc * 20; f += 256) {
        int pl = f / 20, q = f - pl * 20;
        int cl = clsl[pl], c0 = q * 4;
        float4 vv = make_float4(c0 == cl ? 1.0f : 0.0f, c0 + 1 == cl ? 1.0f : 0.0f,
                                c0 + 2 == cl ? 1.0f : 0.0f, c0 + 3 == cl ? 1.0f : 0.0f);
        outcls4[(size_t)p0 * 20 + f] = vv;
    }
}

// ---------------------------------------------------------------------------
// Fallback path (small ws): scratch aliases the bbox-output region, so split
// resolve (C1) and dense writes (C2) into separate launches.
// ---------------------------------------------------------------------------
__global__ __launch_bounds__(256) void phaseC1(const float4* __restrict__ bboxp,
                                               const float4* __restrict__ bboxg,
                                               const int* __restrict__ lbl,
                                               const int* __restrict__ count,
                                               const int* __restrict__ firstg,
                                               float* __restrict__ out0,
                                               float* __restrict__ out1, int P, int N) {
#pragma clang fp contract(off)
    __shared__ float4 gbS[256];
    __shared__ int glS[256];
    if (threadIdx.x < (unsigned)N) {
        gbS[threadIdx.x] = bboxg[threadIdx.x];
        glS[threadIdx.x] = lbl[threadIdx.x];
    }
    __syncthreads();
    int p = blockIdx.x * 256 + threadIdx.x;
    if (p >= P) return;
    int cnt = count[p];
    int gi = 0, pos = 0;
    if (cnt == 1) { gi = firstg[p]; pos = 1; }
    else if (cnt > 1) {
        float4 pb = bboxp[p];
        float pa = fmaxf(pb.z - pb.x, 0.0f) * fmaxf(pb.w - pb.y, 0.0f);
        float best = -1.0f;
        for (int g = 0; g < N; g++) {
            float4 g4 = gbS[g];
            float gar = fmaxf(g4.z - g4.x, 0.0f) * fmaxf(g4.w - g4.y, 0.0f);
            float xx1 = fmaxf(g4.x, pb.x), yy1 = fmaxf(g4.y, pb.y);
            float xx2 = fminf(g4.z, pb.z), yy2 = fminf(g4.w, pb.w);
            float inter = fmaxf(xx2 - xx1, 0.0f) * fmaxf(yy2 - yy1, 0.0f);
            float iou = inter / (((gar + pa) - inter) + EPSF);
            if (iou > best) { best = iou; gi = g; }
        }
        pos = 1;
    }
    out0[p] = (float)gi;
    out1[p] = pos ? (float)glS[gi] : 0.0f;
}

__global__ __launch_bounds__(256) void phaseC2(const float4* __restrict__ bboxg,
                                               const int* __restrict__ lbl,
                                               const float* __restrict__ out0,
                                               float* __restrict__ outcls,
                                               float* __restrict__ outbox, int P, int N) {
    __shared__ float gbb[256 * 4];
    __shared__ int glS[256];
    __shared__ int clsl[256];
    __shared__ int gil[256];
    int tid = threadIdx.x;
    if (tid < N) {
        float4 b = bboxg[tid];
        gbb[tid * 4 + 0] = b.x; gbb[tid * 4 + 1] = b.y;
        gbb[tid * 4 + 2] = b.z; gbb[tid * 4 + 3] = b.w;
        glS[tid] = lbl[tid];
    }
    __syncthreads();
    int p0 = blockIdx.x * 256;
    int nloc = P - p0; if (nloc > 256) nloc = 256;
    if (tid < nloc) {
        int gi = (int)out0[p0 + tid];
        gil[tid] = gi;
        clsl[tid] = glS[gi] - 1;
    }
    __syncthreads();
    for (int f = tid; f < nloc * NCLS; f += 256) {
        int pl = f / NCLS;
        int c  = f - pl * NCLS;
        outcls[(size_t)p0 * NCLS + f] = (c == clsl[pl]) ? 1.0f : 0.0f;
    }
    for (int f = tid; f < nloc * 4; f += 256) {
        int pl = f >> 2, k = f & 3;
        outbox[(size_t)p0 * 4 + f] = gbb[gil[pl] * 4 + k];
    }
}

extern "C" void kernel_launch(void* const* d_in, const int* in_sizes, int n_in,
                              void* d_out, int out_size, void* d_ws, size_t ws_size,
                              hipStream_t stream) {
    const float* cls_pred  = (const float*)d_in[0];
    const float* bbox_pred = (const float*)d_in[1];
    const int*   label_gt  = (const int*)d_in[2];
    const float* bbox_gt   = (const float*)d_in[3];
    int P = in_sizes[1] / 4;
    int N = in_sizes[3] / 4;

    float* out    = (float*)d_out;
    float* out0   = out;
    float* out1   = out + (size_t)P;
    float* outcls = out + (size_t)2 * P;
    float* outbox = out + (size_t)82 * P;

    int pb = (P + 255) / 256;
    int seglen = (P + NSEG - 1) / NSEG;
    int gtiles = (N + GPB - 1) / GPB;
    dim3 gridA1(NSEG, gtiles);
    int setupBlocks = 1 + (P + 1023) / 1024;
    size_t candBytes = (size_t)N * NSEG * TOPK * sizeof(float2);
    size_t needWs = (size_t)P * 8 + candBytes + (size_t)N * 4 + 64;

    if (ws_size >= needWs) {
        // ws: count[P] | firstg[P] | cand | gorder[N]
        int*    count  = (int*)d_ws;
        int*    firstg = count + P;
        float2* cand   = (float2*)(firstg + P);
        int*    gorder = (int*)((char*)cand + candBytes);

        setup<<<setupBlocks, 256, 0, stream>>>(label_gt, count, firstg, gorder, P, N);
        phaseA1<<<gridA1, 512, 0, stream>>>(cls_pred, (const float4*)bbox_pred,
                                            (const float4*)bbox_gt, label_gt, gorder,
                                            cand, P, N, seglen);
        phaseA2<<<N, 512, 0, stream>>>(cand, count, firstg);
        phaseCF<<<pb, 256, 0, stream>>>((const float4*)bbox_pred, (const float4*)bbox_gt,
                                        label_gt, count, firstg, out0, out1,
                                        (float4*)outcls, (float4*)outbox, P, N);
    } else {
        // fallback: scratch inside outbox region
        int*    count  = (int*)outbox;
        int*    firstg = ((int*)outbox) + P;
        float2* cand   = (float2*)(((int*)outbox) + 2 * (size_t)P);
        int*    gorder = (int*)((char*)cand + candBytes);

        setup<<<setupBlocks, 256, 0, stream>>>(label_gt, count, firstg, gorder, P, N);
        phaseA1<<<gridA1, 512, 0, stream>>>(cls_pred, (const float4*)bbox_pred,
                                            (const float4*)bbox_gt, label_gt, gorder,
                                            cand, P, N, seglen);
        phaseC1<<<pb, 256, 0, stream>>>((const float4*)bbox_pred, (const float4*)bbox_gt,
                                        label_gt, count, firstg, out0, out1, P, N);
        phaseC2<<<pb, 256, 0, stream>>>((const float4*)bbox_gt, label_gt, out0,
                                        outcls, outbox, P, N);
    }
}

// Round 10
// 248.575 us; speedup vs baseline: 1.2697x; 1.2697x over previous
//
#include <hip/hip_runtime.h>

#define TOPK 13
#define NCLS 80
#define EPSF 1e-9f
#define NSEG 64           // 2048 blocks = 4 staggered cohorts at 2 blocks/CU
#define GPB  8            // GTs per block (one per wave at selection time)
#define CAP3 512          // per-g candidates: worst-case ~375 at seglen 2344
#define MCAP (64 * TOPK)  // merge scratch entries per wave

// ---------------------------------------------------------------------------
// setup: block 0 sorts GTs by (class,g) -> gorder; blocks 1.. init
// count[P]=0 / firstg[P]=INT_MAX with int4 stores.
// ---------------------------------------------------------------------------
__global__ __launch_bounds__(256) void setup(const int* __restrict__ lbl,
                                             int* __restrict__ count,
                                             int* __restrict__ firstg,
                                             int* __restrict__ gorder, int P, int N) {
    int t = threadIdx.x;
    if (blockIdx.x == 0) {
        __shared__ int key[256];
        key[t] = (t < N) ? ((lbl[t] << 8) | t) : 0x7FFFFFFF;
        __syncthreads();
        for (int k = 2; k <= 256; k <<= 1) {
            for (int j = k >> 1; j >= 1; j >>= 1) {
                int ixj = t ^ j;
                if (ixj > t) {
                    int a = key[t], b = key[ixj];
                    bool up = ((t & k) == 0);
                    if (up ? (a > b) : (a < b)) { key[t] = b; key[ixj] = a; }
                }
                __syncthreads();
            }
        }
        if (t < N) gorder[t] = key[t] & 0xFF;
    } else {
        int base = (blockIdx.x - 1) * 1024 + t * 4;
        if (base + 3 < P) {
            *(int4*)&count[base]  = make_int4(0, 0, 0, 0);
            *(int4*)&firstg[base] = make_int4(0x7FFFFFFF, 0x7FFFFFFF, 0x7FFFFFFF, 0x7FFFFFFF);
        } else {
            for (int i = base; i < P; i++) { count[i] = 0; firstg[i] = 0x7FFFFFFF; }
        }
    }
}

// ---------------------------------------------------------------------------
// phaseA1 (R8 structure, proven 80us at NSEG=32; only NSEG changed):
// grid (NSEG, N/8), 512 threads, separate pbuf+mbuf (70KB LDS, 2 blocks/CU).
// HOT: simple strided overlap filter -> per-g LDS p-lists.
// SPARSE: wave wv exactly evaluates g-slot wv's candidates, per-lane top-13
// with (m desc, p asc) total order, LDS tree merge, write 13 to cand.
// ---------------------------------------------------------------------------
__global__ __launch_bounds__(512, 4) void phaseA1(const float* __restrict__ cls,
                                                  const float4* __restrict__ bboxp,
                                                  const float4* __restrict__ bboxg,
                                                  const int* __restrict__ lbl,
                                                  const int* __restrict__ gorder,
                                                  float2* __restrict__ cand,
                                                  int P, int N, int seglen) {
#pragma clang fp contract(off)
    const int s = blockIdx.x, tile = blockIdx.y, t = threadIdx.x;
    const int wv = t >> 6, lane = t & 63;
    const int pstart = s * seglen;
    int pend = pstart + seglen; if (pend > P) pend = P;

    __shared__ int pbuf[GPB][CAP3];      // 16 KB
    __shared__ float2 mbuf[GPB][MCAP];   // 53.25 KB
    __shared__ int ctr[GPB];

    float4 gb[GPB];
#pragma unroll
    for (int j = 0; j < GPB; j++) {
        int gi8 = tile * GPB + j;
        int gj = (gi8 < N) ? gorder[gi8] : -1;
        gb[j] = (gj >= 0) ? bboxg[gj] : make_float4(0.f, 0.f, 0.f, 0.f);
    }
    if (t < GPB) ctr[t] = 0;
    __syncthreads();

    // ---- HOT filter loop ----
    bool first = true;
    for (int p = pstart + t; p < pend; p += 512) {
        float4 pb = bboxp[p];
        bool force = first && (t < 16);
        first = false;
#pragma unroll
        for (int j = 0; j < GPB; j++) {
            float dx = fminf(gb[j].z, pb.z) - fmaxf(gb[j].x, pb.x);
            float dy = fminf(gb[j].w, pb.w) - fmaxf(gb[j].y, pb.y);
            bool want = ((dx > 0.0f) && (dy > 0.0f)) || force;
            if (want) {
                int slot = atomicAdd(&ctr[j], 1);
                if (slot < CAP3) pbuf[j][slot] = p;
            }
        }
    }
    __syncthreads();

    // ---- SPARSE exact evaluation: wave wv owns g-slot wv ----
    const int gi8 = tile * GPB + wv;
    const bool myValid = gi8 < N;
    const int gj = myValid ? gorder[gi8] : 0;
    const float4 gbw = bboxg[gj];
    const float gaw = fmaxf(gbw.z - gbw.x, 0.0f) * fmaxf(gbw.w - gbw.y, 0.0f);
    const int cidx = lbl[gj] - 1;
    const int rawtotal = ctr[wv];

    float v[TOPK]; int id[TOPK];
#pragma unroll
    for (int k = 0; k < TOPK; k++) { v[k] = -1.0f; id[k] = 0x7FFFFFFF; }

    auto ins = [&](float m, int pp) {
        bool b12 = (m > v[TOPK - 1]) || (m == v[TOPK - 1] && pp < id[TOPK - 1]);
        if (b12) {
#pragma unroll
            for (int k = TOPK - 1; k >= 1; k--) {
                bool a = (m > v[k - 1]) || (m == v[k - 1] && pp < id[k - 1]);
                bool b = (m > v[k]) || (m == v[k] && pp < id[k]);
                float nv = a ? v[k - 1] : (b ? m : v[k]);
                int   ni = a ? id[k - 1] : (b ? pp : id[k]);
                v[k] = nv; id[k] = ni;
            }
            bool a0 = (m > v[0]) || (m == v[0] && pp < id[0]);
            if (a0) { v[0] = m; id[0] = pp; }
        }
    };

    if (rawtotal <= CAP3) {
        for (int e = lane; e < rawtotal; e += 64) {
            int pp = pbuf[wv][e];
            float4 pb = bboxp[pp];
            float sc = cls[(size_t)pp * NCLS + cidx];
            float pa = fmaxf(pb.z - pb.x, 0.0f) * fmaxf(pb.w - pb.y, 0.0f);
            float xx1 = fmaxf(gbw.x, pb.x), yy1 = fmaxf(gbw.y, pb.y);
            float xx2 = fminf(gbw.z, pb.z), yy2 = fminf(gbw.w, pb.w);
            float inter = fmaxf(xx2 - xx1, 0.0f) * fmaxf(yy2 - yy1, 0.0f);
            float iou = inter / (((gaw + pa) - inter) + EPSF);
            float i2 = iou * iou;
            float m = sc * ((i2 * i2) * i2);
            ins(m, pp);
        }
    } else if (myValid) {
        for (int pp = pstart + lane; pp < pend; pp += 64) {  // exact cold fallback
            float4 pb = bboxp[pp];
            float sc = cls[(size_t)pp * NCLS + cidx];
            float pa = fmaxf(pb.z - pb.x, 0.0f) * fmaxf(pb.w - pb.y, 0.0f);
            float xx1 = fmaxf(gbw.x, pb.x), yy1 = fmaxf(gbw.y, pb.y);
            float xx2 = fminf(gbw.z, pb.z), yy2 = fminf(gbw.w, pb.w);
            float inter = fmaxf(xx2 - xx1, 0.0f) * fmaxf(yy2 - yy1, 0.0f);
            float iou = inter / (((gaw + pa) - inter) + EPSF);
            float i2 = iou * iou;
            float m = sc * ((i2 * i2) * i2);
            ins(m, pp);
        }
    }

    // ---- per-wave LDS tree merge (distinct mbuf region per wave) ----
    float2* wl = mbuf[wv];
#pragma unroll
    for (int k = 0; k < TOPK; k++)
        wl[lane * TOPK + k] = make_float2(v[k], __int_as_float(id[k]));
    __syncthreads();
    for (int str = 32; str >= 1; str >>= 1) {
        if (lane < str) {
            float2 merged[TOPK];
            int a = 0, b = 0;
            const int ba = lane * TOPK, bb = (lane + str) * TOPK;
#pragma unroll
            for (int k = 0; k < TOPK; k++) {
                float2 fa = wl[ba + a], fb = wl[bb + b];
                int ia = __float_as_int(fa.y), ib = __float_as_int(fb.y);
                bool takeA = (fa.x > fb.x) || (fa.x == fb.x && ia < ib);
                merged[k] = takeA ? fa : fb;
                a += takeA; b += !takeA;
            }
#pragma unroll
            for (int k = 0; k < TOPK; k++) wl[ba + k] = merged[k];
        }
        __syncthreads();
    }
    if (lane < TOPK && myValid)
        cand[((size_t)gj * NSEG + s) * TOPK + lane] = wl[lane];
}

// ---------------------------------------------------------------------------
// phaseA2: per GT merge NSEG*13=832 candidates -> exact global top-13.
// Per-thread sorted-insert over strided entries, then R2-proven block
// tree-merge with (value desc, index asc) tie-break. 512 threads.
// ---------------------------------------------------------------------------
__global__ __launch_bounds__(512) void phaseA2(const float2* __restrict__ cand,
                                               int* __restrict__ count,
                                               int* __restrict__ firstg) {
    const int g = blockIdx.x;
    const int t = threadIdx.x;
    const int M = NSEG * TOPK;  // 832
    float v[TOPK]; int id[TOPK];
#pragma unroll
    for (int k = 0; k < TOPK; k++) { v[k] = -1.0f; id[k] = 0x7FFFFFFF; }
    for (int e = t; e < M; e += 512) {
        float2 E = cand[(size_t)g * M + e];
        float m = E.x; int pp = __float_as_int(E.y);
        bool b12 = (m > v[TOPK - 1]) || (m == v[TOPK - 1] && pp < id[TOPK - 1]);
        if (b12) {
#pragma unroll
            for (int k = TOPK - 1; k >= 1; k--) {
                bool a = (m > v[k - 1]) || (m == v[k - 1] && pp < id[k - 1]);
                bool b = (m > v[k]) || (m == v[k] && pp < id[k]);
                float nv = a ? v[k - 1] : (b ? m : v[k]);
                int   ni = a ? id[k - 1] : (b ? pp : id[k]);
                v[k] = nv; id[k] = ni;
            }
            bool a0 = (m > v[0]) || (m == v[0] && pp < id[0]);
            if (a0) { v[0] = m; id[0] = pp; }
        }
    }
    __shared__ float sv[512 * TOPK];   // 26.6 KB
    __shared__ int   si[512 * TOPK];   // 26.6 KB
#pragma unroll
    for (int k = 0; k < TOPK; k++) {
        sv[t * TOPK + k] = v[k];
        si[t * TOPK + k] = id[k];
    }
    __syncthreads();
    for (int str = 256; str >= 1; str >>= 1) {
        if (t < str) {
            float* va = &sv[t * TOPK];
            int*   ia = &si[t * TOPK];
            float* vb = &sv[(t + str) * TOPK];
            int*   ib = &si[(t + str) * TOPK];
            float mv[TOPK]; int mi[TOPK];
            int a = 0, b = 0;
#pragma unroll
            for (int k = 0; k < TOPK; k++) {
                float fa = va[a], fb = vb[b];
                int   xa = ia[a], xb = ib[b];
                bool takeA = (fa > fb) || (fa == fb && xa < xb);
                if (takeA) { mv[k] = fa; mi[k] = xa; a++; }
                else       { mv[k] = fb; mi[k] = xb; b++; }
            }
#pragma unroll
            for (int k = 0; k < TOPK; k++) { va[k] = mv[k]; ia[k] = mi[k]; }
        }
        __syncthreads();
    }
    if (t < TOPK && sv[0] > EPSF) {
        int pi = si[t];
        atomicAdd(&count[pi], 1);
        atomicMin(&firstg[pi], g);
    }
}

// ---------------------------------------------------------------------------
// phaseCF (ws path): fused resolve + all outputs, dense coalesced writes.
// ---------------------------------------------------------------------------
__global__ __launch_bounds__(256) void phaseCF(const float4* __restrict__ bboxp,
                                               const float4* __restrict__ bboxg,
                                               const int* __restrict__ lbl,
                                               const int* __restrict__ count,
                                               const int* __restrict__ firstg,
                                               float* __restrict__ out0,
                                               float* __restrict__ out1,
                                               float4* __restrict__ outcls4,
                                               float4* __restrict__ outbox4, int P, int N) {
#pragma clang fp contract(off)
    __shared__ float4 gbS[256];
    __shared__ int glS[256];
    __shared__ int clsl[256];
    int t = threadIdx.x;
    if (t < N) { gbS[t] = bboxg[t]; glS[t] = lbl[t]; }
    __syncthreads();
    int p0 = blockIdx.x * 256;
    int nloc = P - p0; if (nloc > 256) nloc = 256;
    if (t < nloc) {
        int p = p0 + t;
        int cnt = count[p];
        int gi = 0, pos = 0;
        if (cnt == 1) { gi = firstg[p]; pos = 1; }
        else if (cnt > 1) {
            float4 pb = bboxp[p];
            float pa = fmaxf(pb.z - pb.x, 0.0f) * fmaxf(pb.w - pb.y, 0.0f);
            float best = -1.0f;
            for (int g = 0; g < N; g++) {
                float4 g4 = gbS[g];
                float gar = fmaxf(g4.z - g4.x, 0.0f) * fmaxf(g4.w - g4.y, 0.0f);
                float xx1 = fmaxf(g4.x, pb.x), yy1 = fmaxf(g4.y, pb.y);
                float xx2 = fminf(g4.z, pb.z), yy2 = fminf(g4.w, pb.w);
                float inter = fmaxf(xx2 - xx1, 0.0f) * fmaxf(yy2 - yy1, 0.0f);
                float iou = inter / (((gar + pa) - inter) + EPSF);
                if (iou > best) { best = iou; gi = g; }   // strict > == first-max
            }
            pos = 1;
        }
        out0[p] = (float)gi;
        out1[p] = pos ? (float)glS[gi] : 0.0f;
        clsl[t] = glS[gi] - 1;
        outbox4[p] = gbS[gi];
    }
    __syncthreads();
    for (int f = t; f < nloc * 20; f += 256) {
        int pl = f / 20, q = f - pl * 20;
        int cl = clsl[pl], c0 = q * 4;
        float4 vv = make_float4(c0 == cl ? 1.0f : 0.0f, c0 + 1 == cl ? 1.0f : 0.0f,
                                c0 + 2 == cl ? 1.0f : 0.0f, c0 + 3 == cl ? 1.0f : 0.0f);
        outcls4[(size_t)p0 * 20 + f] = vv;
    }
}

// ---------------------------------------------------------------------------
// Fallback path (small ws): count/firstg alias outbox; cand/gorder alias the
// 48MB outcls region (consumed by phaseA2 before phaseC2 writes outcls).
// ---------------------------------------------------------------------------
__global__ __launch_bounds__(256) void phaseC1(const float4* __restrict__ bboxp,
                                               const float4* __restrict__ bboxg,
                                               const int* __restrict__ lbl,
                                               const int* __restrict__ count,
                                               const int* __restrict__ firstg,
                                               float* __restrict__ out0,
                                               float* __restrict__ out1, int P, int N) {
#pragma clang fp contract(off)
    __shared__ float4 gbS[256];
    __shared__ int glS[256];
    if (threadIdx.x < (unsigned)N) {
        gbS[threadIdx.x] = bboxg[threadIdx.x];
        glS[threadIdx.x] = lbl[threadIdx.x];
    }
    __syncthreads();
    int p = blockIdx.x * 256 + threadIdx.x;
    if (p >= P) return;
    int cnt = count[p];
    int gi = 0, pos = 0;
    if (cnt == 1) { gi = firstg[p]; pos = 1; }
    else if (cnt > 1) {
        float4 pb = bboxp[p];
        float pa = fmaxf(pb.z - pb.x, 0.0f) * fmaxf(pb.w - pb.y, 0.0f);
        float best = -1.0f;
        for (int g = 0; g < N; g++) {
            float4 g4 = gbS[g];
            float gar = fmaxf(g4.z - g4.x, 0.0f) * fmaxf(g4.w - g4.y, 0.0f);
            float xx1 = fmaxf(g4.x, pb.x), yy1 = fmaxf(g4.y, pb.y);
            float xx2 = fminf(g4.z, pb.z), yy2 = fminf(g4.w, pb.w);
            float inter = fmaxf(xx2 - xx1, 0.0f) * fmaxf(yy2 - yy1, 0.0f);
            float iou = inter / (((gar + pa) - inter) + EPSF);
            if (iou > best) { best = iou; gi = g; }
        }
        pos = 1;
    }
    out0[p] = (float)gi;
    out1[p] = pos ? (float)glS[gi] : 0.0f;
}

__global__ __launch_bounds__(256) void phaseC2(const float4* __restrict__ bboxg,
                                               const int* __restrict__ lbl,
                                               const float* __restrict__ out0,
                                               float* __restrict__ outcls,
                                               float* __restrict__ outbox, int P, int N) {
    __shared__ float gbb[256 * 4];
    __shared__ int glS[256];
    __shared__ int clsl[256];
    __shared__ int gil[256];
    int tid = threadIdx.x;
    if (tid < N) {
        float4 b = bboxg[tid];
        gbb[tid * 4 + 0] = b.x; gbb[tid * 4 + 1] = b.y;
        gbb[tid * 4 + 2] = b.z; gbb[tid * 4 + 3] = b.w;
        glS[tid] = lbl[tid];
    }
    __syncthreads();
    int p0 = blockIdx.x * 256;
    int nloc = P - p0; if (nloc > 256) nloc = 256;
    if (tid < nloc) {
        int gi = (int)out0[p0 + tid];
        gil[tid] = gi;
        clsl[tid] = glS[gi] - 1;
    }
    __syncthreads();
    for (int f = tid; f < nloc * NCLS; f += 256) {
        int pl = f / NCLS;
        int c  = f - pl * NCLS;
        outcls[(size_t)p0 * NCLS + f] = (c == clsl[pl]) ? 1.0f : 0.0f;
    }
    for (int f = tid; f < nloc * 4; f += 256) {
        int pl = f >> 2, k = f & 3;
        outbox[(size_t)p0 * 4 + f] = gbb[gil[pl] * 4 + k];
    }
}

extern "C" void kernel_launch(void* const* d_in, const int* in_sizes, int n_in,
                              void* d_out, int out_size, void* d_ws, size_t ws_size,
                              hipStream_t stream) {
    const float* cls_pred  = (const float*)d_in[0];
    const float* bbox_pred = (const float*)d_in[1];
    const int*   label_gt  = (const int*)d_in[2];
    const float* bbox_gt   = (const float*)d_in[3];
    int P = in_sizes[1] / 4;
    int N = in_sizes[3] / 4;

    float* out    = (float*)d_out;
    float* out0   = out;
    float* out1   = out + (size_t)P;
    float* outcls = out + (size_t)2 * P;
    float* outbox = out + (size_t)82 * P;

    int pb = (P + 255) / 256;
    int seglen = (P + NSEG - 1) / NSEG;
    int gtiles = (N + GPB - 1) / GPB;
    dim3 gridA1(NSEG, gtiles);
    int setupBlocks = 1 + (P + 1023) / 1024;
    size_t candBytes = (size_t)N * NSEG * TOPK * sizeof(float2);
    size_t needWs = (size_t)P * 8 + candBytes + (size_t)N * 4 + 64;

    if (ws_size >= needWs) {
        // ws: count[P] | firstg[P] | cand | gorder[N]
        int*    count  = (int*)d_ws;
        int*    firstg = count + P;
        float2* cand   = (float2*)(firstg + P);
        int*    gorder = (int*)((char*)cand + candBytes);

        setup<<<setupBlocks, 256, 0, stream>>>(label_gt, count, firstg, gorder, P, N);
        phaseA1<<<gridA1, 512, 0, stream>>>(cls_pred, (const float4*)bbox_pred,
                                            (const float4*)bbox_gt, label_gt, gorder,
                                            cand, P, N, seglen);
        phaseA2<<<N, 512, 0, stream>>>(cand, count, firstg);
        phaseCF<<<pb, 256, 0, stream>>>((const float4*)bbox_pred, (const float4*)bbox_gt,
                                        label_gt, count, firstg, out0, out1,
                                        (float4*)outcls, (float4*)outbox, P, N);
    } else {
        // fallback: count/firstg in outbox region (1.2MB of 2.4MB);
        // cand+gorder in the 48MB outcls region (dead until phaseC2).
        int*    count  = (int*)outbox;
        int*    firstg = ((int*)outbox) + P;
        float2* cand   = (float2*)outcls;
        int*    gorder = (int*)((char*)cand + candBytes);

        setup<<<setupBlocks, 256, 0, stream>>>(label_gt, count, firstg, gorder, P, N);
        phaseA1<<<gridA1, 512, 0, stream>>>(cls_pred, (const float4*)bbox_pred,
                                            (const float4*)bbox_gt, label_gt, gorder,
                                            cand, P, N, seglen);
        phaseA2<<<N, 512, 0, stream>>>(cand, count, firstg);
        phaseC1<<<pb, 256, 0, stream>>>((const float4*)bbox_pred, (const float4*)bbox_gt,
                                        label_gt, count, firstg, out0, out1, P, N);
        phaseC2<<<pb, 256, 0, stream>>>((const float4*)bbox_gt, label_gt, out0,
                                        outcls, outbox, P, N);
    }
}

// Round 11
// 217.972 us; speedup vs baseline: 1.4480x; 1.1404x over previous
//
#include <hip/hip_runtime.h>

#define TOPK 13
#define NCLS 80
#define EPSF 1e-9f
#define NSEG 32           // seglen 4688: worst-case ~431 candidates < CAP3 (no overflow)
#define GPB  8            // GTs per block (one per wave at selection time)
#define CAP3 512          // per-g candidate p-indices
#define MCAP (64 * TOPK)  // merge scratch entries per wave

// ---------------------------------------------------------------------------
// setup: block 0 sorts GTs by (class,g) -> gorder; blocks 1.. init
// count[P]=0 / firstg[P]=INT_MAX with int4 stores.
// ---------------------------------------------------------------------------
__global__ __launch_bounds__(256) void setup(const int* __restrict__ lbl,
                                             int* __restrict__ count,
                                             int* __restrict__ firstg,
                                             int* __restrict__ gorder, int P, int N) {
    int t = threadIdx.x;
    if (blockIdx.x == 0) {
        __shared__ int key[256];
        key[t] = (t < N) ? ((lbl[t] << 8) | t) : 0x7FFFFFFF;
        __syncthreads();
        for (int k = 2; k <= 256; k <<= 1) {
            for (int j = k >> 1; j >= 1; j >>= 1) {
                int ixj = t ^ j;
                if (ixj > t) {
                    int a = key[t], b = key[ixj];
                    bool up = ((t & k) == 0);
                    if (up ? (a > b) : (a < b)) { key[t] = b; key[ixj] = a; }
                }
                __syncthreads();
            }
        }
        if (t < N) gorder[t] = key[t] & 0xFF;
    } else {
        int base = (blockIdx.x - 1) * 1024 + t * 4;
        if (base + 3 < P) {
            *(int4*)&count[base]  = make_int4(0, 0, 0, 0);
            *(int4*)&firstg[base] = make_int4(0x7FFFFFFF, 0x7FFFFFFF, 0x7FFFFFFF, 0x7FFFFFFF);
        } else {
            for (int i = base; i < P; i++) { count[i] = 0; firstg[i] = 0x7FFFFFFF; }
        }
    }
}

// ---------------------------------------------------------------------------
// phaseA1: R8 structure (proven 80us) + ONE change: pbuf aliases mbuf's first
// 16KB -> LDS 53.3KB -> 3 blocks/CU (24 waves). Barrier added between the
// eval-phase pbuf reads and the merge-phase mbuf writes (alias safety).
// NSEG=32 keeps worst-case candidates (~431) under CAP3 — no overflow
// (the actual cause of the R7/R9 regressions).
// ---------------------------------------------------------------------------
__global__ __launch_bounds__(512, 6) void phaseA1(const float* __restrict__ cls,
                                                  const float4* __restrict__ bboxp,
                                                  const float4* __restrict__ bboxg,
                                                  const int* __restrict__ lbl,
                                                  const int* __restrict__ gorder,
                                                  float2* __restrict__ cand,
                                                  int P, int N, int seglen) {
#pragma clang fp contract(off)
    const int s = blockIdx.x, tile = blockIdx.y, t = threadIdx.x;
    const int wv = t >> 6, lane = t & 63;
    const int pstart = s * seglen;
    int pend = pstart + seglen; if (pend > P) pend = P;

    __shared__ float2 mbuf[GPB][MCAP];   // 53248 B; first 16 KB doubles as pbuf
    __shared__ int ctr[GPB];
    int* pbuf = (int*)&mbuf[0][0];       // pbuf[j*CAP3 + slot], j<8 -> 16 KB

    float4 gb[GPB];
#pragma unroll
    for (int j = 0; j < GPB; j++) {
        int gi8 = tile * GPB + j;
        int gj = (gi8 < N) ? gorder[gi8] : -1;
        gb[j] = (gj >= 0) ? bboxg[gj] : make_float4(0.f, 0.f, 0.f, 0.f);
    }
    if (t < GPB) ctr[t] = 0;
    __syncthreads();

    // ---- HOT filter loop (identical to R8) ----
    bool first = true;
    for (int p = pstart + t; p < pend; p += 512) {
        float4 pb = bboxp[p];
        bool force = first && (t < 16);
        first = false;
#pragma unroll
        for (int j = 0; j < GPB; j++) {
            float dx = fminf(gb[j].z, pb.z) - fmaxf(gb[j].x, pb.x);
            float dy = fminf(gb[j].w, pb.w) - fmaxf(gb[j].y, pb.y);
            bool want = ((dx > 0.0f) && (dy > 0.0f)) || force;
            if (want) {
                int slot = atomicAdd(&ctr[j], 1);
                if (slot < CAP3) pbuf[j * CAP3 + slot] = p;
            }
        }
    }
    __syncthreads();

    // ---- SPARSE exact evaluation: wave wv owns g-slot wv ----
    const int gi8 = tile * GPB + wv;
    const bool myValid = gi8 < N;
    const int gj = myValid ? gorder[gi8] : 0;
    const float4 gbw = bboxg[gj];
    const float gaw = fmaxf(gbw.z - gbw.x, 0.0f) * fmaxf(gbw.w - gbw.y, 0.0f);
    const int cidx = lbl[gj] - 1;
    const int rawtotal = ctr[wv];

    float v[TOPK]; int id[TOPK];
#pragma unroll
    for (int k = 0; k < TOPK; k++) { v[k] = -1.0f; id[k] = 0x7FFFFFFF; }

    auto ins = [&](float m, int pp) {
        bool b12 = (m > v[TOPK - 1]) || (m == v[TOPK - 1] && pp < id[TOPK - 1]);
        if (b12) {
#pragma unroll
            for (int k = TOPK - 1; k >= 1; k--) {
                bool a = (m > v[k - 1]) || (m == v[k - 1] && pp < id[k - 1]);
                bool b = (m > v[k]) || (m == v[k] && pp < id[k]);
                float nv = a ? v[k - 1] : (b ? m : v[k]);
                int   ni = a ? id[k - 1] : (b ? pp : id[k]);
                v[k] = nv; id[k] = ni;
            }
            bool a0 = (m > v[0]) || (m == v[0] && pp < id[0]);
            if (a0) { v[0] = m; id[0] = pp; }
        }
    };

    if (rawtotal <= CAP3) {
        for (int e = lane; e < rawtotal; e += 64) {
            int pp = pbuf[wv * CAP3 + e];
            float4 pb = bboxp[pp];
            float sc = cls[(size_t)pp * NCLS + cidx];
            float pa = fmaxf(pb.z - pb.x, 0.0f) * fmaxf(pb.w - pb.y, 0.0f);
            float xx1 = fmaxf(gbw.x, pb.x), yy1 = fmaxf(gbw.y, pb.y);
            float xx2 = fminf(gbw.z, pb.z), yy2 = fminf(gbw.w, pb.w);
            float inter = fmaxf(xx2 - xx1, 0.0f) * fmaxf(yy2 - yy1, 0.0f);
            float iou = inter / (((gaw + pa) - inter) + EPSF);
            float i2 = iou * iou;
            float m = sc * ((i2 * i2) * i2);
            ins(m, pp);
        }
    } else if (myValid) {
        for (int pp = pstart + lane; pp < pend; pp += 64) {  // exact cold fallback
            float4 pb = bboxp[pp];
            float sc = cls[(size_t)pp * NCLS + cidx];
            float pa = fmaxf(pb.z - pb.x, 0.0f) * fmaxf(pb.w - pb.y, 0.0f);
            float xx1 = fmaxf(gbw.x, pb.x), yy1 = fmaxf(gbw.y, pb.y);
            float xx2 = fminf(gbw.z, pb.z), yy2 = fminf(gbw.w, pb.w);
            float inter = fmaxf(xx2 - xx1, 0.0f) * fmaxf(yy2 - yy1, 0.0f);
            float iou = inter / (((gaw + pa) - inter) + EPSF);
            float i2 = iou * iou;
            float m = sc * ((i2 * i2) * i2);
            ins(m, pp);
        }
    }
    __syncthreads();   // ALL waves' pbuf reads done before merge overwrites alias

    // ---- per-wave LDS tree merge (each wave owns mbuf[wv]) ----
    float2* wl = mbuf[wv];
#pragma unroll
    for (int k = 0; k < TOPK; k++)
        wl[lane * TOPK + k] = make_float2(v[k], __int_as_float(id[k]));
    __syncthreads();
    for (int str = 32; str >= 1; str >>= 1) {
        if (lane < str) {
            float2 merged[TOPK];
            int a = 0, b = 0;
            const int ba = lane * TOPK, bb = (lane + str) * TOPK;
#pragma unroll
            for (int k = 0; k < TOPK; k++) {
                float2 fa = wl[ba + a], fb = wl[bb + b];
                int ia = __float_as_int(fa.y), ib = __float_as_int(fb.y);
                bool takeA = (fa.x > fb.x) || (fa.x == fb.x && ia < ib);
                merged[k] = takeA ? fa : fb;
                a += takeA; b += !takeA;
            }
#pragma unroll
            for (int k = 0; k < TOPK; k++) wl[ba + k] = merged[k];
        }
        __syncthreads();
    }
    if (lane < TOPK && myValid)
        cand[((size_t)gj * NSEG + s) * TOPK + lane] = wl[lane];
}

// ---------------------------------------------------------------------------
// phaseA2: per GT merge NSEG*13=416 candidates -> exact global top-13 via a
// 512-element bitonic sort, then scatter count/firstg atomics if max > eps.
// ---------------------------------------------------------------------------
__global__ __launch_bounds__(512) void phaseA2(const float2* __restrict__ cand,
                                               int* __restrict__ count,
                                               int* __restrict__ firstg) {
    const int g = blockIdx.x;
    const int t = threadIdx.x;
    const int M = NSEG * TOPK;  // 416
    __shared__ float cv[512];
    __shared__ int   ci[512];
    if (t < M) {
        float2 e = cand[(size_t)g * M + t];
        cv[t] = e.x; ci[t] = __float_as_int(e.y);
    } else {
        cv[t] = -1.0f; ci[t] = 0x7FFFFFFF;
    }
    __syncthreads();
    for (int k = 2; k <= 512; k <<= 1) {
        for (int j = k >> 1; j >= 1; j >>= 1) {
            int ixj = t ^ j;
            if (ixj > t) {
                float va = cv[t], vb = cv[ixj];
                int   ia = ci[t], ib = ci[ixj];
                bool aBeforeB = (va > vb) || (va == vb && ia < ib);
                bool dirFwd = ((t & k) == 0);
                bool doswap = dirFwd ? !aBeforeB : aBeforeB;
                if (doswap) { cv[t] = vb; ci[t] = ib; cv[ixj] = va; ci[ixj] = ia; }
            }
            __syncthreads();
        }
    }
    if (t < TOPK && cv[0] > EPSF) {
        int pi = ci[t];
        atomicAdd(&count[pi], 1);
        atomicMin(&firstg[pi], g);
    }
}

// ---------------------------------------------------------------------------
// phaseCF (ws path): fused resolve + all outputs, dense coalesced writes.
// ---------------------------------------------------------------------------
__global__ __launch_bounds__(256) void phaseCF(const float4* __restrict__ bboxp,
                                               const float4* __restrict__ bboxg,
                                               const int* __restrict__ lbl,
                                               const int* __restrict__ count,
                                               const int* __restrict__ firstg,
                                               float* __restrict__ out0,
                                               float* __restrict__ out1,
                                               float4* __restrict__ outcls4,
                                               float4* __restrict__ outbox4, int P, int N) {
#pragma clang fp contract(off)
    __shared__ float4 gbS[256];
    __shared__ int glS[256];
    __shared__ int clsl[256];
    int t = threadIdx.x;
    if (t < N) { gbS[t] = bboxg[t]; glS[t] = lbl[t]; }
    __syncthreads();
    int p0 = blockIdx.x * 256;
    int nloc = P - p0; if (nloc > 256) nloc = 256;
    if (t < nloc) {
        int p = p0 + t;
        int cnt = count[p];
        int gi = 0, pos = 0;
        if (cnt == 1) { gi = firstg[p]; pos = 1; }
        else if (cnt > 1) {
            float4 pb = bboxp[p];
            float pa = fmaxf(pb.z - pb.x, 0.0f) * fmaxf(pb.w - pb.y, 0.0f);
            float best = -1.0f;
            for (int g = 0; g < N; g++) {
                float4 g4 = gbS[g];
                float gar = fmaxf(g4.z - g4.x, 0.0f) * fmaxf(g4.w - g4.y, 0.0f);
                float xx1 = fmaxf(g4.x, pb.x), yy1 = fmaxf(g4.y, pb.y);
                float xx2 = fminf(g4.z, pb.z), yy2 = fminf(g4.w, pb.w);
                float inter = fmaxf(xx2 - xx1, 0.0f) * fmaxf(yy2 - yy1, 0.0f);
                float iou = inter / (((gar + pa) - inter) + EPSF);
                if (iou > best) { best = iou; gi = g; }   // strict > == first-max
            }
            pos = 1;
        }
        out0[p] = (float)gi;
        out1[p] = pos ? (float)glS[gi] : 0.0f;
        clsl[t] = glS[gi] - 1;
        outbox4[p] = gbS[gi];
    }
    __syncthreads();
    for (int f = t; f < nloc * 20; f += 256) {
        int pl = f / 20, q = f - pl * 20;
        int cl = clsl[pl], c0 = q * 4;
        float4 vv = make_float4(c0 == cl ? 1.0f : 0.0f, c0 + 1 == cl ? 1.0f : 0.0f,
                                c0 + 2 == cl ? 1.0f : 0.0f, c0 + 3 == cl ? 1.0f : 0.0f);
        outcls4[(size_t)p0 * 20 + f] = vv;
    }
}

// ---------------------------------------------------------------------------
// Fallback path (small ws): scratch aliases the output regions; split C1/C2.
// ---------------------------------------------------------------------------
__global__ __launch_bounds__(256) void phaseC1(const float4* __restrict__ bboxp,
                                               const float4* __restrict__ bboxg,
                                               const int* __restrict__ lbl,
                                               const int* __restrict__ count,
                                               const int* __restrict__ firstg,
                                               float* __restrict__ out0,
                                               float* __restrict__ out1, int P, int N) {
#pragma clang fp contract(off)
    __shared__ float4 gbS[256];
    __shared__ int glS[256];
    if (threadIdx.x < (unsigned)N) {
        gbS[threadIdx.x] = bboxg[threadIdx.x];
        glS[threadIdx.x] = lbl[threadIdx.x];
    }
    __syncthreads();
    int p = blockIdx.x * 256 + threadIdx.x;
    if (p >= P) return;
    int cnt = count[p];
    int gi = 0, pos = 0;
    if (cnt == 1) { gi = firstg[p]; pos = 1; }
    else if (cnt > 1) {
        float4 pb = bboxp[p];
        float pa = fmaxf(pb.z - pb.x, 0.0f) * fmaxf(pb.w - pb.y, 0.0f);
        float best = -1.0f;
        for (int g = 0; g < N; g++) {
            float4 g4 = gbS[g];
            float gar = fmaxf(g4.z - g4.x, 0.0f) * fmaxf(g4.w - g4.y, 0.0f);
            float xx1 = fmaxf(g4.x, pb.x), yy1 = fmaxf(g4.y, pb.y);
            float xx2 = fminf(g4.z, pb.z), yy2 = fminf(g4.w, pb.w);
            float inter = fmaxf(xx2 - xx1, 0.0f) * fmaxf(yy2 - yy1, 0.0f);
            float iou = inter / (((gar + pa) - inter) + EPSF);
            if (iou > best) { best = iou; gi = g; }
        }
        pos = 1;
    }
    out0[p] = (float)gi;
    out1[p] = pos ? (float)glS[gi] : 0.0f;
}

__global__ __launch_bounds__(256) void phaseC2(const float4* __restrict__ bboxg,
                                               const int* __restrict__ lbl,
                                               const float* __restrict__ out0,
                                               float* __restrict__ outcls,
                                               float* __restrict__ outbox, int P, int N) {
    __shared__ float gbb[256 * 4];
    __shared__ int glS[256];
    __shared__ int clsl[256];
    __shared__ int gil[256];
    int tid = threadIdx.x;
    if (tid < N) {
        float4 b = bboxg[tid];
        gbb[tid * 4 + 0] = b.x; gbb[tid * 4 + 1] = b.y;
        gbb[tid * 4 + 2] = b.z; gbb[tid * 4 + 3] = b.w;
        glS[tid] = lbl[tid];
    }
    __syncthreads();
    int p0 = blockIdx.x * 256;
    int nloc = P - p0; if (nloc > 256) nloc = 256;
    if (tid < nloc) {
        int gi = (int)out0[p0 + tid];
        gil[tid] = gi;
        clsl[tid] = glS[gi] - 1;
    }
    __syncthreads();
    for (int f = tid; f < nloc * NCLS; f += 256) {
        int pl = f / NCLS;
        int c  = f - pl * NCLS;
        outcls[(size_t)p0 * NCLS + f] = (c == clsl[pl]) ? 1.0f : 0.0f;
    }
    for (int f = tid; f < nloc * 4; f += 256) {
        int pl = f >> 2, k = f & 3;
        outbox[(size_t)p0 * 4 + f] = gbb[gil[pl] * 4 + k];
    }
}

extern "C" void kernel_launch(void* const* d_in, const int* in_sizes, int n_in,
                              void* d_out, int out_size, void* d_ws, size_t ws_size,
                              hipStream_t stream) {
    const float* cls_pred  = (const float*)d_in[0];
    const float* bbox_pred = (const float*)d_in[1];
    const int*   label_gt  = (const int*)d_in[2];
    const float* bbox_gt   = (const float*)d_in[3];
    int P = in_sizes[1] / 4;
    int N = in_sizes[3] / 4;

    float* out    = (float*)d_out;
    float* out0   = out;
    float* out1   = out + (size_t)P;
    float* outcls = out + (size_t)2 * P;
    float* outbox = out + (size_t)82 * P;

    int pb = (P + 255) / 256;
    int seglen = (P + NSEG - 1) / NSEG;
    int gtiles = (N + GPB - 1) / GPB;
    dim3 gridA1(NSEG, gtiles);
    int setupBlocks = 1 + (P + 1023) / 1024;
    size_t candBytes = (size_t)N * NSEG * TOPK * sizeof(float2);
    size_t needWs = (size_t)P * 8 + candBytes + (size_t)N * 4 + 64;

    if (ws_size >= needWs) {
        // ws: count[P] | firstg[P] | cand | gorder[N]
        int*    count  = (int*)d_ws;
        int*    firstg = count + P;
        float2* cand   = (float2*)(firstg + P);
        int*    gorder = (int*)((char*)cand + candBytes);

        setup<<<setupBlocks, 256, 0, stream>>>(label_gt, count, firstg, gorder, P, N);
        phaseA1<<<gridA1, 512, 0, stream>>>(cls_pred, (const float4*)bbox_pred,
                                            (const float4*)bbox_gt, label_gt, gorder,
                                            cand, P, N, seglen);
        phaseA2<<<N, 512, 0, stream>>>(cand, count, firstg);
        phaseCF<<<pb, 256, 0, stream>>>((const float4*)bbox_pred, (const float4*)bbox_gt,
                                        label_gt, count, firstg, out0, out1,
                                        (float4*)outcls, (float4*)outbox, P, N);
    } else {
        // fallback: count/firstg in outbox region; cand/gorder in the 48MB
        // outcls region (dead until phaseC2 writes it).
        int*    count  = (int*)outbox;
        int*    firstg = ((int*)outbox) + P;
        float2* cand   = (float2*)outcls;
        int*    gorder = (int*)((char*)cand + candBytes);

        setup<<<setupBlocks, 256, 0, stream>>>(label_gt, count, firstg, gorder, P, N);
        phaseA1<<<gridA1, 512, 0, stream>>>(cls_pred, (const float4*)bbox_pred,
                                            (const float4*)bbox_gt, label_gt, gorder,
                                            cand, P, N, seglen);
        phaseC1<<<pb, 256, 0, stream>>>((const float4*)bbox_pred, (const float4*)bbox_gt,
                                        label_gt, count, firstg, out0, out1, P, N);
        phaseC2<<<pb, 256, 0, stream>>>((const float4*)bbox_gt, label_gt, out0,
                                        outcls, outbox, P, N);
    }
}

// Round 12
// 214.412 us; speedup vs baseline: 1.4720x; 1.0166x over previous
//
#include <hip/hip_runtime.h>

#define TOPK 13
#define NCLS 80
#define EPSF 1e-9f
#define NSEG 32           // seglen 4688: worst-case ~490 candidates < CAP3 (no overflow)
#define GPB  8            // GTs per block (one per wave at selection time)
#define CAP3 512          // per-g candidate p-indices
#define MCAP (64 * TOPK)  // merge scratch entries per wave

// ---------------------------------------------------------------------------
// setup: block 0 sorts GTs by (class,g) -> gorder; blocks 1.. init
// count[P]=0 / firstg[P]=INT_MAX with int4 stores.
// ---------------------------------------------------------------------------
__global__ __launch_bounds__(256) void setup(const int* __restrict__ lbl,
                                             int* __restrict__ count,
                                             int* __restrict__ firstg,
                                             int* __restrict__ gorder, int P, int N) {
    int t = threadIdx.x;
    if (blockIdx.x == 0) {
        __shared__ int key[256];
        key[t] = (t < N) ? ((lbl[t] << 8) | t) : 0x7FFFFFFF;
        __syncthreads();
        for (int k = 2; k <= 256; k <<= 1) {
            for (int j = k >> 1; j >= 1; j >>= 1) {
                int ixj = t ^ j;
                if (ixj > t) {
                    int a = key[t], b = key[ixj];
                    bool up = ((t & k) == 0);
                    if (up ? (a > b) : (a < b)) { key[t] = b; key[ixj] = a; }
                }
                __syncthreads();
            }
        }
        if (t < N) gorder[t] = key[t] & 0xFF;
    } else {
        int base = (blockIdx.x - 1) * 1024 + t * 4;
        if (base + 3 < P) {
            *(int4*)&count[base]  = make_int4(0, 0, 0, 0);
            *(int4*)&firstg[base] = make_int4(0x7FFFFFFF, 0x7FFFFFFF, 0x7FFFFFFF, 0x7FFFFFFF);
        } else {
            for (int i = base; i < P; i++) { count[i] = 0; firstg[i] = 0x7FFFFFFF; }
        }
    }
}

// ---------------------------------------------------------------------------
// phaseA1: R11 structure (79us) + MLP: peeled 4x-unrolled filter loop
// (4 independent bboxp loads in flight) and 2-way unrolled sparse-eval
// gather. This is the isolated test of the R7 unroll delta.
// ---------------------------------------------------------------------------
__global__ __launch_bounds__(512, 6) void phaseA1(const float* __restrict__ cls,
                                                  const float4* __restrict__ bboxp,
                                                  const float4* __restrict__ bboxg,
                                                  const int* __restrict__ lbl,
                                                  const int* __restrict__ gorder,
                                                  float2* __restrict__ cand,
                                                  int P, int N, int seglen) {
#pragma clang fp contract(off)
    const int s = blockIdx.x, tile = blockIdx.y, t = threadIdx.x;
    const int wv = t >> 6, lane = t & 63;
    const int pstart = s * seglen;
    int pend = pstart + seglen; if (pend > P) pend = P;

    __shared__ float2 mbuf[GPB][MCAP];   // 53248 B; first 16 KB doubles as pbuf
    __shared__ int ctr[GPB];
    int* pbuf = (int*)&mbuf[0][0];       // pbuf[j*CAP3 + slot], j<8 -> 16 KB

    float4 gb[GPB];
#pragma unroll
    for (int j = 0; j < GPB; j++) {
        int gi8 = tile * GPB + j;
        int gj = (gi8 < N) ? gorder[gi8] : -1;
        gb[j] = (gj >= 0) ? bboxg[gj] : make_float4(0.f, 0.f, 0.f, 0.f);
    }
    if (t < GPB) ctr[t] = 0;
    __syncthreads();

    auto testapp = [&](float4 pb, int p, bool force) {
#pragma unroll
        for (int j = 0; j < GPB; j++) {
            float dx = fminf(gb[j].z, pb.z) - fmaxf(gb[j].x, pb.x);
            float dy = fminf(gb[j].w, pb.w) - fmaxf(gb[j].y, pb.y);
            bool want = ((dx > 0.0f) && (dy > 0.0f)) || force;
            if (want) {
                int slot = atomicAdd(&ctr[j], 1);
                if (slot < CAP3) pbuf[j * CAP3 + slot] = p;
            }
        }
    };

    // ---- HOT filter: peeled first element (forced-16), then 4x unroll ----
    int p = pstart + t;
    if (p < pend) { testapp(bboxp[p], p, t < 16); p += 512; }
    for (; p + 1536 < pend; p += 2048) {     // 4 independent loads in flight
        float4 pb0 = bboxp[p];
        float4 pb1 = bboxp[p + 512];
        float4 pb2 = bboxp[p + 1024];
        float4 pb3 = bboxp[p + 1536];
        testapp(pb0, p, false);
        testapp(pb1, p + 512, false);
        testapp(pb2, p + 1024, false);
        testapp(pb3, p + 1536, false);
    }
    for (; p < pend; p += 512) testapp(bboxp[p], p, false);
    __syncthreads();

    // ---- SPARSE exact evaluation: wave wv owns g-slot wv ----
    const int gi8 = tile * GPB + wv;
    const bool myValid = gi8 < N;
    const int gj = myValid ? gorder[gi8] : 0;
    const float4 gbw = bboxg[gj];
    const float gaw = fmaxf(gbw.z - gbw.x, 0.0f) * fmaxf(gbw.w - gbw.y, 0.0f);
    const int cidx = lbl[gj] - 1;
    const int rawtotal = ctr[wv];

    float v[TOPK]; int id[TOPK];
#pragma unroll
    for (int k = 0; k < TOPK; k++) { v[k] = -1.0f; id[k] = 0x7FFFFFFF; }

    auto ins = [&](float m, int pp) {
        bool b12 = (m > v[TOPK - 1]) || (m == v[TOPK - 1] && pp < id[TOPK - 1]);
        if (b12) {
#pragma unroll
            for (int k = TOPK - 1; k >= 1; k--) {
                bool a = (m > v[k - 1]) || (m == v[k - 1] && pp < id[k - 1]);
                bool b = (m > v[k]) || (m == v[k] && pp < id[k]);
                float nv = a ? v[k - 1] : (b ? m : v[k]);
                int   ni = a ? id[k - 1] : (b ? pp : id[k]);
                v[k] = nv; id[k] = ni;
            }
            bool a0 = (m > v[0]) || (m == v[0] && pp < id[0]);
            if (a0) { v[0] = m; id[0] = pp; }
        }
    };

    auto evalm = [&](float4 pb, float sc) -> float {
        float pa = fmaxf(pb.z - pb.x, 0.0f) * fmaxf(pb.w - pb.y, 0.0f);
        float xx1 = fmaxf(gbw.x, pb.x), yy1 = fmaxf(gbw.y, pb.y);
        float xx2 = fminf(gbw.z, pb.z), yy2 = fminf(gbw.w, pb.w);
        float inter = fmaxf(xx2 - xx1, 0.0f) * fmaxf(yy2 - yy1, 0.0f);
        float iou = inter / (((gaw + pa) - inter) + EPSF);
        float i2 = iou * iou;
        return sc * ((i2 * i2) * i2);
    };

    if (rawtotal <= CAP3) {
        int e = lane;
        for (; e + 64 < rawtotal; e += 128) {    // 2 independent gathers in flight
            int pp0 = pbuf[wv * CAP3 + e];
            int pp1 = pbuf[wv * CAP3 + e + 64];
            float4 pb0 = bboxp[pp0];
            float4 pb1 = bboxp[pp1];
            float sc0 = cls[(size_t)pp0 * NCLS + cidx];
            float sc1 = cls[(size_t)pp1 * NCLS + cidx];
            float m0 = evalm(pb0, sc0);
            float m1 = evalm(pb1, sc1);
            ins(m0, pp0);
            ins(m1, pp1);
        }
        for (; e < rawtotal; e += 64) {
            int pp = pbuf[wv * CAP3 + e];
            float4 pb = bboxp[pp];
            float sc = cls[(size_t)pp * NCLS + cidx];
            ins(evalm(pb, sc), pp);
        }
    } else if (myValid) {
        for (int pp = pstart + lane; pp < pend; pp += 64) {  // exact cold fallback
            float4 pb = bboxp[pp];
            float sc = cls[(size_t)pp * NCLS + cidx];
            ins(evalm(pb, sc), pp);
        }
    }
    __syncthreads();   // ALL waves' pbuf reads done before merge overwrites alias

    // ---- per-wave LDS tree merge (each wave owns mbuf[wv]) ----
    float2* wl = mbuf[wv];
#pragma unroll
    for (int k = 0; k < TOPK; k++)
        wl[lane * TOPK + k] = make_float2(v[k], __int_as_float(id[k]));
    __syncthreads();
    for (int str = 32; str >= 1; str >>= 1) {
        if (lane < str) {
            float2 merged[TOPK];
            int a = 0, b = 0;
            const int ba = lane * TOPK, bb = (lane + str) * TOPK;
#pragma unroll
            for (int k = 0; k < TOPK; k++) {
                float2 fa = wl[ba + a], fb = wl[bb + b];
                int ia = __float_as_int(fa.y), ib = __float_as_int(fb.y);
                bool takeA = (fa.x > fb.x) || (fa.x == fb.x && ia < ib);
                merged[k] = takeA ? fa : fb;
                a += takeA; b += !takeA;
            }
#pragma unroll
            for (int k = 0; k < TOPK; k++) wl[ba + k] = merged[k];
        }
        __syncthreads();
    }
    if (lane < TOPK && myValid)
        cand[((size_t)gj * NSEG + s) * TOPK + lane] = wl[lane];
}

// ---------------------------------------------------------------------------
// phaseA2: per GT merge NSEG*13=416 candidates -> exact global top-13 via a
// 512-element bitonic sort, then scatter count/firstg atomics if max > eps.
// ---------------------------------------------------------------------------
__global__ __launch_bounds__(512) void phaseA2(const float2* __restrict__ cand,
                                               int* __restrict__ count,
                                               int* __restrict__ firstg) {
    const int g = blockIdx.x;
    const int t = threadIdx.x;
    const int M = NSEG * TOPK;  // 416
    __shared__ float cv[512];
    __shared__ int   ci[512];
    if (t < M) {
        float2 e = cand[(size_t)g * M + t];
        cv[t] = e.x; ci[t] = __float_as_int(e.y);
    } else {
        cv[t] = -1.0f; ci[t] = 0x7FFFFFFF;
    }
    __syncthreads();
    for (int k = 2; k <= 512; k <<= 1) {
        for (int j = k >> 1; j >= 1; j >>= 1) {
            int ixj = t ^ j;
            if (ixj > t) {
                float va = cv[t], vb = cv[ixj];
                int   ia = ci[t], ib = ci[ixj];
                bool aBeforeB = (va > vb) || (va == vb && ia < ib);
                bool dirFwd = ((t & k) == 0);
                bool doswap = dirFwd ? !aBeforeB : aBeforeB;
                if (doswap) { cv[t] = vb; ci[t] = ib; cv[ixj] = va; ci[ixj] = ia; }
            }
            __syncthreads();
        }
    }
    if (t < TOPK && cv[0] > EPSF) {
        int pi = ci[t];
        atomicAdd(&count[pi], 1);
        atomicMin(&firstg[pi], g);
    }
}

// ---------------------------------------------------------------------------
// phaseCF (ws path): fused resolve + all outputs, dense coalesced writes.
// ---------------------------------------------------------------------------
__global__ __launch_bounds__(256) void phaseCF(const float4* __restrict__ bboxp,
                                               const float4* __restrict__ bboxg,
                                               const int* __restrict__ lbl,
                                               const int* __restrict__ count,
                                               const int* __restrict__ firstg,
                                               float* __restrict__ out0,
                                               float* __restrict__ out1,
                                               float4* __restrict__ outcls4,
                                               float4* __restrict__ outbox4, int P, int N) {
#pragma clang fp contract(off)
    __shared__ float4 gbS[256];
    __shared__ int glS[256];
    __shared__ int clsl[256];
    int t = threadIdx.x;
    if (t < N) { gbS[t] = bboxg[t]; glS[t] = lbl[t]; }
    __syncthreads();
    int p0 = blockIdx.x * 256;
    int nloc = P - p0; if (nloc > 256) nloc = 256;
    if (t < nloc) {
        int p = p0 + t;
        int cnt = count[p];
        int gi = 0, pos = 0;
        if (cnt == 1) { gi = firstg[p]; pos = 1; }
        else if (cnt > 1) {
            float4 pb = bboxp[p];
            float pa = fmaxf(pb.z - pb.x, 0.0f) * fmaxf(pb.w - pb.y, 0.0f);
            float best = -1.0f;
            for (int g = 0; g < N; g++) {
                float4 g4 = gbS[g];
                float gar = fmaxf(g4.z - g4.x, 0.0f) * fmaxf(g4.w - g4.y, 0.0f);
                float xx1 = fmaxf(g4.x, pb.x), yy1 = fmaxf(g4.y, pb.y);
                float xx2 = fminf(g4.z, pb.z), yy2 = fminf(g4.w, pb.w);
                float inter = fmaxf(xx2 - xx1, 0.0f) * fmaxf(yy2 - yy1, 0.0f);
                float iou = inter / (((gar + pa) - inter) + EPSF);
                if (iou > best) { best = iou; gi = g; }   // strict > == first-max
            }
            pos = 1;
        }
        out0[p] = (float)gi;
        out1[p] = pos ? (float)glS[gi] : 0.0f;
        clsl[t] = glS[gi] - 1;
        outbox4[p] = gbS[gi];
    }
    __syncthreads();
    for (int f = t; f < nloc * 20; f += 256) {
        int pl = f / 20, q = f - pl * 20;
        int cl = clsl[pl], c0 = q * 4;
        float4 vv = make_float4(c0 == cl ? 1.0f : 0.0f, c0 + 1 == cl ? 1.0f : 0.0f,
                                c0 + 2 == cl ? 1.0f : 0.0f, c0 + 3 == cl ? 1.0f : 0.0f);
        outcls4[(size_t)p0 * 20 + f] = vv;
    }
}

// ---------------------------------------------------------------------------
// Fallback path (small ws): scratch aliases the output regions; split C1/C2.
// ---------------------------------------------------------------------------
__global__ __launch_bounds__(256) void phaseC1(const float4* __restrict__ bboxp,
                                               const float4* __restrict__ bboxg,
                                               const int* __restrict__ lbl,
                                               const int* __restrict__ count,
                                               const int* __restrict__ firstg,
                                               float* __restrict__ out0,
                                               float* __restrict__ out1, int P, int N) {
#pragma clang fp contract(off)
    __shared__ float4 gbS[256];
    __shared__ int glS[256];
    if (threadIdx.x < (unsigned)N) {
        gbS[threadIdx.x] = bboxg[threadIdx.x];
        glS[threadIdx.x] = lbl[threadIdx.x];
    }
    __syncthreads();
    int p = blockIdx.x * 256 + threadIdx.x;
    if (p >= P) return;
    int cnt = count[p];
    int gi = 0, pos = 0;
    if (cnt == 1) { gi = firstg[p]; pos = 1; }
    else if (cnt > 1) {
        float4 pb = bboxp[p];
        float pa = fmaxf(pb.z - pb.x, 0.0f) * fmaxf(pb.w - pb.y, 0.0f);
        float best = -1.0f;
        for (int g = 0; g < N; g++) {
            float4 g4 = gbS[g];
            float gar = fmaxf(g4.z - g4.x, 0.0f) * fmaxf(g4.w - g4.y, 0.0f);
            float xx1 = fmaxf(g4.x, pb.x), yy1 = fmaxf(g4.y, pb.y);
            float xx2 = fminf(g4.z, pb.z), yy2 = fminf(g4.w, pb.w);
            float inter = fmaxf(xx2 - xx1, 0.0f) * fmaxf(yy2 - yy1, 0.0f);
            float iou = inter / (((gar + pa) - inter) + EPSF);
            if (iou > best) { best = iou; gi = g; }
        }
        pos = 1;
    }
    out0[p] = (float)gi;
    out1[p] = pos ? (float)glS[gi] : 0.0f;
}

__global__ __launch_bounds__(256) void phaseC2(const float4* __restrict__ bboxg,
                                               const int* __restrict__ lbl,
                                               const float* __restrict__ out0,
                                               float* __restrict__ outcls,
                                               float* __restrict__ outbox, int P, int N) {
    __shared__ float gbb[256 * 4];
    __shared__ int glS[256];
    __shared__ int clsl[256];
    __shared__ int gil[256];
    int tid = threadIdx.x;
    if (tid < N) {
        float4 b = bboxg[tid];
        gbb[tid * 4 + 0] = b.x; gbb[tid * 4 + 1] = b.y;
        gbb[tid * 4 + 2] = b.z; gbb[tid * 4 + 3] = b.w;
        glS[tid] = lbl[tid];
    }
    __syncthreads();
    int p0 = blockIdx.x * 256;
    int nloc = P - p0; if (nloc > 256) nloc = 256;
    if (tid < nloc) {
        int gi = (int)out0[p0 + tid];
        gil[tid] = gi;
        clsl[tid] = glS[gi] - 1;
    }
    __syncthreads();
    for (int f = tid; f < nloc * NCLS; f += 256) {
        int pl = f / NCLS;
        int c  = f - pl * NCLS;
        outcls[(size_t)p0 * NCLS + f] = (c == clsl[pl]) ? 1.0f : 0.0f;
    }
    for (int f = tid; f < nloc * 4; f += 256) {
        int pl = f >> 2, k = f & 3;
        outbox[(size_t)p0 * 4 + f] = gbb[gil[pl] * 4 + k];
    }
}

extern "C" void kernel_launch(void* const* d_in, const int* in_sizes, int n_in,
                              void* d_out, int out_size, void* d_ws, size_t ws_size,
                              hipStream_t stream) {
    const float* cls_pred  = (const float*)d_in[0];
    const float* bbox_pred = (const float*)d_in[1];
    const int*   label_gt  = (const int*)d_in[2];
    const float* bbox_gt   = (const float*)d_in[3];
    int P = in_sizes[1] / 4;
    int N = in_sizes[3] / 4;

    float* out    = (float*)d_out;
    float* out0   = out;
    float* out1   = out + (size_t)P;
    float* outcls = out + (size_t)2 * P;
    float* outbox = out + (size_t)82 * P;

    int pb = (P + 255) / 256;
    int seglen = (P + NSEG - 1) / NSEG;
    int gtiles = (N + GPB - 1) / GPB;
    dim3 gridA1(NSEG, gtiles);
    int setupBlocks = 1 + (P + 1023) / 1024;
    size_t candBytes = (size_t)N * NSEG * TOPK * sizeof(float2);
    size_t needWs = (size_t)P * 8 + candBytes + (size_t)N * 4 + 64;

    if (ws_size >= needWs) {
        // ws: count[P] | firstg[P] | cand | gorder[N]
        int*    count  = (int*)d_ws;
        int*    firstg = count + P;
        float2* cand   = (float2*)(firstg + P);
        int*    gorder = (int*)((char*)cand + candBytes);

        setup<<<setupBlocks, 256, 0, stream>>>(label_gt, count, firstg, gorder, P, N);
        phaseA1<<<gridA1, 512, 0, stream>>>(cls_pred, (const float4*)bbox_pred,
                                            (const float4*)bbox_gt, label_gt, gorder,
                                            cand, P, N, seglen);
        phaseA2<<<N, 512, 0, stream>>>(cand, count, firstg);
        phaseCF<<<pb, 256, 0, stream>>>((const float4*)bbox_pred, (const float4*)bbox_gt,
                                        label_gt, count, firstg, out0, out1,
                                        (float4*)outcls, (float4*)outbox, P, N);
    } else {
        // fallback: count/firstg in outbox region; cand/gorder in the 48MB
        // outcls region (dead until phaseC2 writes it).
        int*    count  = (int*)outbox;
        int*    firstg = ((int*)outbox) + P;
        float2* cand   = (float2*)outcls;
        int*    gorder = (int*)((char*)cand + candBytes);

        setup<<<setupBlocks, 256, 0, stream>>>(label_gt, count, firstg, gorder, P, N);
        phaseA1<<<gridA1, 512, 0, stream>>>(cls_pred, (const float4*)bbox_pred,
                                            (const float4*)bbox_gt, label_gt, gorder,
                                            cand, P, N, seglen);
        phaseC1<<<pb, 256, 0, stream>>>((const float4*)bbox_pred, (const float4*)bbox_gt,
                                        label_gt, count, firstg, out0, out1, P, N);
        phaseC2<<<pb, 256, 0, stream>>>((const float4*)bbox_gt, label_gt, out0,
                                        outcls, outbox, P, N);
    }
}